// Round 4
// baseline (8813.177 us; speedup 1.0000x reference)
//
#include <hip/hip_runtime.h>
#include <math.h>

// Problem constants
#define VOCAB 50000
#define EMB   1024
#define H2    512
#define R4    2048      // 4*H2 gate rows per direction
#define TLEN  4096
#define NTAGS 5
#define STARTT 3
#define STOPT  4
#define NEGV  (-10000.0f)

#define NWG   32        // WGs in recurrence; each owns a slice of BOTH dirs
#define SLICE 16        // h-elements per WG per direction (512/32)

typedef unsigned long long u64;
typedef _Float16 half2v __attribute__((ext_vector_type(2)));

#define ALOAD64(p)    __hip_atomic_load((p), __ATOMIC_RELAXED, __HIP_MEMORY_SCOPE_AGENT)
#define ASTORE64(p,v) __hip_atomic_store((p), (v), __ATOMIC_RELAXED, __HIP_MEMORY_SCOPE_AGENT)

// Fast activations (validated exact-pass in R2/R3 at bf16-level check)
__device__ __forceinline__ float fsig(float x) {
    return __builtin_amdgcn_rcpf(1.f + __expf(-x));
}
__device__ __forceinline__ float ftanh(float x) {
    return 1.f - 2.f * __builtin_amdgcn_rcpf(1.f + __expf(2.f * x));
}

// DPP butterfly add: x += lanes-permuted x. VALU-pipe cross-lane (no LDS).
template <int CTRL>
__device__ __forceinline__ float dppadd(float x) {
    int o = __builtin_amdgcn_update_dpp(0, __float_as_int(x), CTRL, 0xf, 0xf, true);
    return x + __int_as_float(o);
}
// Reduce over 16 contiguous lanes (one DPP row): xor1, xor2, half-swap, 8-swap.
#define RED16(a) do { \
    a = dppadd<0xB1>(a);   /* quad_perm [1,0,3,2]  = xor 1 */ \
    a = dppadd<0x4E>(a);   /* quad_perm [2,3,0,1]  = xor 2 */ \
    a = dppadd<0x141>(a);  /* row_half_mirror      = xor-ish 4 */ \
    a = dppadd<0x128>(a);  /* row_ror:8            = xor-ish 8 */ \
} while (0)

// -------------------------------------------------------------------------
// Kernel 1: G[dir][t][e][gate] = Wih_dir[gate*512+e,:] . embed[sent[t],:] + biases
// Interleaved [e][gate] epilogue so the recurrence producer reads one float4.
// -------------------------------------------------------------------------
__global__ __launch_bounds__(256) void input_gemm(
    const int* __restrict__ sent, const float* __restrict__ embed,
    const float* __restrict__ WihF, const float* __restrict__ WihB,
    const float* __restrict__ bihF, const float* __restrict__ bhhF,
    const float* __restrict__ bihB, const float* __restrict__ bhhB,
    float* __restrict__ G)
{
    __shared__ float As[32 * 64];   // [k][t]
    __shared__ float Bs[32 * 64];   // [k][n]
    const int tid = threadIdx.x;
    const int tm = blockIdx.x * 64;
    const int tn = blockIdx.y * 64;
    const int dir = blockIdx.z;
    const float* Wih = dir ? WihB : WihF;

    const int lr = tid >> 2;
    const int lp = tid & 3;
    const int srow = sent[tm + lr];
    const float* arow = embed + (size_t)srow * EMB;
    const float* brow = Wih + (size_t)(tn + lr) * EMB;

    const int mt = (tid & 15) * 4;
    const int nt = (tid >> 4) * 4;
    float acc[4][4] = {};

    for (int k0 = 0; k0 < EMB; k0 += 32) {
        float4 a0 = *(const float4*)(arow + k0 + lp * 8);
        float4 a1 = *(const float4*)(arow + k0 + lp * 8 + 4);
        float4 b0 = *(const float4*)(brow + k0 + lp * 8);
        float4 b1 = *(const float4*)(brow + k0 + lp * 8 + 4);
        __syncthreads();
        const int kb = lp * 8;
        As[(kb + 0) * 64 + lr] = a0.x; As[(kb + 1) * 64 + lr] = a0.y;
        As[(kb + 2) * 64 + lr] = a0.z; As[(kb + 3) * 64 + lr] = a0.w;
        As[(kb + 4) * 64 + lr] = a1.x; As[(kb + 5) * 64 + lr] = a1.y;
        As[(kb + 6) * 64 + lr] = a1.z; As[(kb + 7) * 64 + lr] = a1.w;
        Bs[(kb + 0) * 64 + lr] = b0.x; Bs[(kb + 1) * 64 + lr] = b0.y;
        Bs[(kb + 2) * 64 + lr] = b0.z; Bs[(kb + 3) * 64 + lr] = b0.w;
        Bs[(kb + 4) * 64 + lr] = b1.x; Bs[(kb + 5) * 64 + lr] = b1.y;
        Bs[(kb + 6) * 64 + lr] = b1.z; Bs[(kb + 7) * 64 + lr] = b1.w;
        __syncthreads();
        #pragma unroll
        for (int k = 0; k < 32; ++k) {
            float4 av = *(const float4*)(As + k * 64 + mt);
            float4 bv = *(const float4*)(Bs + k * 64 + nt);
            acc[0][0] += av.x * bv.x; acc[0][1] += av.x * bv.y; acc[0][2] += av.x * bv.z; acc[0][3] += av.x * bv.w;
            acc[1][0] += av.y * bv.x; acc[1][1] += av.y * bv.y; acc[1][2] += av.y * bv.z; acc[1][3] += av.y * bv.w;
            acc[2][0] += av.z * bv.x; acc[2][1] += av.z * bv.y; acc[2][2] += av.z * bv.z; acc[2][3] += av.z * bv.w;
            acc[3][0] += av.w * bv.x; acc[3][1] += av.w * bv.y; acc[3][2] += av.w * bv.z; acc[3][3] += av.w * bv.w;
        }
    }

    const float* bih = dir ? bihB : bihF;
    const float* bhh = dir ? bhhB : bhhF;
    float bias[4];
    #pragma unroll
    for (int jj = 0; jj < 4; ++jj)
        bias[jj] = bih[tn + nt + jj] + bhh[tn + nt + jj];
    float* Gd = G + (size_t)dir * TLEN * R4;
    #pragma unroll
    for (int ii = 0; ii < 4; ++ii) {
        #pragma unroll
        for (int jj = 0; jj < 4; ++jj) {
            int n = tn + nt + jj;
            int gate = n >> 9, ee = n & 511;
            Gd[(size_t)(tm + mt + ii) * R4 + ee * 4 + gate] = acc[ii][jj] + bias[jj];
        }
    }
}

// -------------------------------------------------------------------------
// Kernel 2: persistent BiLSTM recurrence — paired directions per WG.
// 32 WGs x 256 threads; WG owns h-elems [base..base+15] of BOTH directions.
// Alternating d0/d1 phases hide mailbox propagation: each dir's poll data
// was stored ~one phase earlier by producers, so prefetched polls hit.
// Lane (wl=tid&63): e_loc = wl>>4 (elem within wave), seg = wl&15 (32-col
// h segment). Lane computes all 4 gates of elem (wave*4+e_loc) over its
// 32 cols: f16 weights (v_dot2_f32_f16, fp32 accum), 4 ds_read_b128, DPP
// 16-lane reduction (no LDS, no gather). seg==0 lane owns c and stores.
// -------------------------------------------------------------------------
__global__ __launch_bounds__(256, 1) void lstm_rec(
    const float* __restrict__ WhhF, const float* __restrict__ WhhB,
    const float* __restrict__ h0, const float* __restrict__ c0,
    const float* __restrict__ G, float* __restrict__ hs,
    u64* hbuf)
{
    const int tid  = threadIdx.x;
    const int base = blockIdx.x * SLICE;
    const int wave = tid >> 6;
    const int wl   = tid & 63;
    const int e_loc = wl >> 4;
    const int seg   = wl & 15;
    const int e     = wave * 4 + e_loc;      // 0..15
    const bool prod = (seg == 0);

    // f16 weights, both dirs: [gate][k] half2 pairs of cols seg*32+2k,2k+1
    half2v WA[4][16], WB[4][16];
    #pragma unroll
    for (int g = 0; g < 4; ++g) {
        const float* sa = WhhF + (size_t)(g * H2 + base + e) * H2 + seg * 32;
        const float* sb = WhhB + (size_t)(g * H2 + base + e) * H2 + seg * 32;
        #pragma unroll
        for (int k = 0; k < 16; ++k) {
            half2v wa, wb;
            wa[0] = (_Float16)sa[2 * k]; wa[1] = (_Float16)sa[2 * k + 1];
            wb[0] = (_Float16)sb[2 * k]; wb[1] = (_Float16)sb[2 * k + 1];
            WA[g][k] = wa; WB[g][k] = wb;
        }
    }

    // h staging: [dir][seg*20 + pos] dwords (2 f16 each); pitch 20 dwords
    // keeps 16B alignment for b128 and <=2-way bank aliasing (free).
    __shared__ __align__(16) unsigned hstg[2][16 * 20 + 8];

    u64* hb0 = hbuf;                 // dir0 [parity][512]
    u64* hb1 = hbuf + 2 * H2;        // dir1
    const int slot = tid * 2;
    const int spos = (tid >> 4) * 20 + (tid & 15);

    float cc0 = 0.f, cc1 = 0.f;
    if (prod) {
        cc0 = c0[0 * H2 + base + e];
        cc1 = c0[1 * H2 + base + e];
        ASTORE64(hb0 + base + e, ((u64)1u << 32) | __float_as_uint(h0[0 * H2 + base + e]));
        ASTORE64(hb1 + base + e, ((u64)1u << 32) | __float_as_uint(h0[1 * H2 + base + e]));
    }

    const float* G0 = G;
    const float* G1 = G + (size_t)TLEN * R4;
    float* hs0 = hs;
    float* hs1 = hs + (size_t)TLEN * H2;

    // Initial prefetches
    u64 p0a = ALOAD64(hb0 + slot), p0b = ALOAD64(hb0 + slot + 1);
    float4 gA = *(const float4*)(G0 + (base + e) * 4);                       // t=0
    float4 gB = *(const float4*)(G1 + (size_t)(TLEN - 1) * R4 + (base + e) * 4); // t=T-1

    #define DOT16(WARR, DBUF, A0, A1, A2, A3) do {                          \
        const uint4* Hr = (const uint4*)&hstg[DBUF][seg * 20];              \
        uint4 q0 = Hr[0], q1 = Hr[1], q2 = Hr[2], q3 = Hr[3];               \
        unsigned xs[16] = {q0.x,q0.y,q0.z,q0.w, q1.x,q1.y,q1.z,q1.w,        \
                           q2.x,q2.y,q2.z,q2.w, q3.x,q3.y,q3.z,q3.w};       \
        _Pragma("unroll")                                                   \
        for (int k = 0; k < 16; ++k) {                                      \
            half2v x = __builtin_bit_cast(half2v, xs[k]);                   \
            A0 = __builtin_amdgcn_fdot2(WARR[0][k], x, A0, false);          \
            A1 = __builtin_amdgcn_fdot2(WARR[1][k], x, A1, false);          \
            A2 = __builtin_amdgcn_fdot2(WARR[2][k], x, A2, false);          \
            A3 = __builtin_amdgcn_fdot2(WARR[3][k], x, A3, false);          \
        } } while (0)

    for (int s = 0; s < TLEN; ++s) {
        const unsigned want = (unsigned)(s + 1);
        const int rp = s & 1, wp = (s + 1) & 1;
        const int snx = (s + 1 < TLEN) ? s + 1 : s;

        // ================= D0 phase =================
        while ((unsigned)(p0a >> 32) != want || (unsigned)(p0b >> 32) != want) {
            p0a = ALOAD64(hb0 + rp * H2 + slot);
            p0b = ALOAD64(hb0 + rp * H2 + slot + 1);
        }
        {
            half2v hp;
            hp[0] = (_Float16)__uint_as_float((unsigned)p0a);
            hp[1] = (_Float16)__uint_as_float((unsigned)p0b);
            hstg[0][spos] = __builtin_bit_cast(unsigned, hp);
        }
        __syncthreads();   // vmcnt drain cheap: all outstanding loads consumed

        // Prefetches issued AFTER the barrier so its vmcnt(0) doesn't stall them
        u64 p1a = ALOAD64(hb1 + rp * H2 + slot);
        u64 p1b = ALOAD64(hb1 + rp * H2 + slot + 1);
        float4 gAn = *(const float4*)(G0 + (size_t)snx * R4 + (base + e) * 4);

        float a0 = 0.f, a1 = 0.f, a2 = 0.f, a3 = 0.f;
        DOT16(WA, 0, a0, a1, a2, a3);
        RED16(a0); RED16(a1); RED16(a2); RED16(a3);

        if (prod) {
            float i_ = fsig(a0 + gA.x);
            float f_ = fsig(a1 + gA.y);
            float g_ = ftanh(a2 + gA.z);
            float o_ = fsig(a3 + gA.w);
            cc0 = f_ * cc0 + i_ * g_;
            float hn = o_ * ftanh(cc0);
            ASTORE64(hb0 + wp * H2 + base + e,
                     ((u64)(unsigned)(s + 2) << 32) | __float_as_uint(hn));
            hs0[(size_t)s * H2 + base + e] = hn;   // dir0: t = s
        }
        gA = gAn;

        // ================= D1 phase =================
        while ((unsigned)(p1a >> 32) != want || (unsigned)(p1b >> 32) != want) {
            p1a = ALOAD64(hb1 + rp * H2 + slot);
            p1b = ALOAD64(hb1 + rp * H2 + slot + 1);
        }
        {
            half2v hp;
            hp[0] = (_Float16)__uint_as_float((unsigned)p1a);
            hp[1] = (_Float16)__uint_as_float((unsigned)p1b);
            hstg[1][spos] = __builtin_bit_cast(unsigned, hp);
        }
        __syncthreads();

        p0a = ALOAD64(hb0 + wp * H2 + slot);       // prefetch next d0 (want s+2)
        p0b = ALOAD64(hb0 + wp * H2 + slot + 1);
        float4 gBn = *(const float4*)(G1 + (size_t)(TLEN - 1 - snx) * R4 + (base + e) * 4);

        float b0 = 0.f, b1 = 0.f, b2 = 0.f, b3 = 0.f;
        DOT16(WB, 1, b0, b1, b2, b3);
        RED16(b0); RED16(b1); RED16(b2); RED16(b3);

        if (prod) {
            float i_ = fsig(b0 + gB.x);
            float f_ = fsig(b1 + gB.y);
            float g_ = ftanh(b2 + gB.z);
            float o_ = fsig(b3 + gB.w);
            cc1 = f_ * cc1 + i_ * g_;
            float hn = o_ * ftanh(cc1);
            ASTORE64(hb1 + wp * H2 + base + e,
                     ((u64)(unsigned)(s + 2) << 32) | __float_as_uint(hn));
            hs1[(size_t)(TLEN - 1 - s) * H2 + base + e] = hn;  // dir1: t = T-1-s
        }
        gB = gBn;
    }
    #undef DOT16
}

// -------------------------------------------------------------------------
// Kernel 3: feats[t][j] = concat(hf[t], hb[t]) . Wout[j] + bout[j]
// -------------------------------------------------------------------------
__global__ __launch_bounds__(64) void feat_kernel(
    const float* __restrict__ hs, const float* __restrict__ Wout,
    const float* __restrict__ bout, float* __restrict__ feats)
{
    const int t = blockIdx.x;
    const int lane = threadIdx.x;
    const float* hf = hs + (size_t)t * H2;
    const float* hb = hs + (size_t)TLEN * H2 + (size_t)t * H2;
    float x[16];
    #pragma unroll
    for (int r = 0; r < 8; ++r) x[r] = hf[lane + r * 64];
    #pragma unroll
    for (int r = 0; r < 8; ++r) x[8 + r] = hb[lane + r * 64];
    for (int j = 0; j < NTAGS; ++j) {
        const float* wr = Wout + (size_t)j * EMB;
        float p = 0.f;
        #pragma unroll
        for (int r = 0; r < 8; ++r) p += x[r] * wr[lane + r * 64];
        #pragma unroll
        for (int r = 0; r < 8; ++r) p += x[8 + r] * wr[H2 + lane + r * 64];
        #pragma unroll
        for (int off = 32; off > 0; off >>= 1) p += __shfl_down(p, off);
        if (lane == 0) feats[t * NTAGS + j] = p + bout[j];
    }
}

// -------------------------------------------------------------------------
// Kernel 4: Viterbi forward scan + backtrace, single wave.
// -------------------------------------------------------------------------
__global__ __launch_bounds__(64) void viterbi_kernel(
    const float* __restrict__ feats, const float* __restrict__ trans,
    float* __restrict__ out)
{
    __shared__ unsigned bp[TLEN];
    __shared__ float fch[256 * NTAGS];
    const int lane = threadIdx.x;
    const bool act = lane < 25;
    const int j = act ? (lane / 5) : 0;
    const int i = act ? (lane % 5) : 0;
    const int j5 = j * 5;
    const float tji = act ? trans[j * 5 + i] : -1e30f;
    float fv = (i == STARTT) ? 0.f : NEGV;

    for (int c0 = 0; c0 < TLEN; c0 += 256) {
        __syncthreads();
        for (int m = lane; m < 256 * NTAGS; m += 64) fch[m] = feats[c0 * NTAGS + m];
        __syncthreads();
        for (int tt = 0; tt < 256; ++tt) {
            float score = fv + tji;
            float v0 = __shfl(score, j5 + 0);
            float v1 = __shfl(score, j5 + 1);
            float v2 = __shfl(score, j5 + 2);
            float v3 = __shfl(score, j5 + 3);
            float v4 = __shfl(score, j5 + 4);
            float mm = v0; int mi = 0;
            if (v1 > mm) { mm = v1; mi = 1; }
            if (v2 > mm) { mm = v2; mi = 2; }
            if (v3 > mm) { mm = v3; mi = 3; }
            if (v4 > mm) { mm = v4; mi = 4; }
            float fnew = mm + fch[tt * NTAGS + j];
            unsigned word = ((unsigned)__shfl(mi, 0)  & 7u)
                          | (((unsigned)__shfl(mi, 5)  & 7u) << 3)
                          | (((unsigned)__shfl(mi, 10) & 7u) << 6)
                          | (((unsigned)__shfl(mi, 15) & 7u) << 9)
                          | (((unsigned)__shfl(mi, 20) & 7u) << 12);
            if (lane == 0) bp[c0 + tt] = word;
            fv = __shfl(fnew, i * 5);
        }
    }
    __syncthreads();

    float tstop = (lane < 5) ? trans[STOPT * 5 + lane] : -1e30f;
    float term = fv + tstop;
    float b0 = __shfl(term, 0), b1 = __shfl(term, 1), b2 = __shfl(term, 2);
    float b3 = __shfl(term, 3), b4 = __shfl(term, 4);
    float bsc = b0; int best = 0;
    if (b1 > bsc) { bsc = b1; best = 1; }
    if (b2 > bsc) { bsc = b2; best = 2; }
    if (b3 > bsc) { bsc = b3; best = 3; }
    if (b4 > bsc) { bsc = b4; best = 4; }

    if (lane == 0) {
        out[0] = bsc;
        int tag = best;
        out[TLEN] = (float)tag;
        #pragma unroll 16
        for (int t = TLEN - 1; t >= 1; --t) {
            tag = (int)((bp[t] >> (3 * tag)) & 7u);
            out[t] = (float)tag;
        }
    }
}

// -------------------------------------------------------------------------
// Launcher
// -------------------------------------------------------------------------
extern "C" void kernel_launch(void* const* d_in, const int* in_sizes, int n_in,
                              void* d_out, int out_size, void* d_ws, size_t ws_size,
                              hipStream_t stream) {
    const int*   sent  = (const int*)d_in[0];
    const float* h0    = (const float*)d_in[1];
    const float* c0    = (const float*)d_in[2];
    const float* embed = (const float*)d_in[3];
    const float* Wih_f = (const float*)d_in[4];
    const float* Whh_f = (const float*)d_in[5];
    const float* bih_f = (const float*)d_in[6];
    const float* bhh_f = (const float*)d_in[7];
    const float* Wih_b = (const float*)d_in[8];
    const float* Whh_b = (const float*)d_in[9];
    const float* bih_b = (const float*)d_in[10];
    const float* bhh_b = (const float*)d_in[11];
    const float* Wout  = (const float*)d_in[12];
    const float* bout  = (const float*)d_in[13];
    const float* trans = (const float*)d_in[14];

    char* ws = (char*)d_ws;
    float*    G     = (float*)(ws);                 // 2*4096*2048 f32 = 64 MB
    float*    hs    = (float*)(ws + 67108864);      // 2*4096*512  f32 = 16 MB
    u64*      hbuf  = (u64*)(ws + 83886080);        // 2 dirs * 2 parity * 512 u64 = 16 KB
    float*    feats = (float*)(ws + 83918848);      // 4096*5 f32

    input_gemm<<<dim3(TLEN / 64, R4 / 64, 2), 256, 0, stream>>>(
        sent, embed, Wih_f, Wih_b, bih_f, bhh_f, bih_b, bhh_b, G);
    lstm_rec<<<NWG, 256, 0, stream>>>(Whh_f, Whh_b, h0, c0, G, hs, hbuf);
    feat_kernel<<<TLEN, 64, 0, stream>>>(hs, Wout, bout, feats);
    viterbi_kernel<<<1, 64, 0, stream>>>(feats, trans, (float*)d_out);
}